// Round 9
// baseline (289.009 us; speedup 1.0000x reference)
//
#include <hip/hip_runtime.h>

namespace {

constexpr int Ldim = 6400;   // rows (h0*w0)
constexpr int Sdim = 6400;   // cols (h1*w1)
constexpr float INV_CT = 0.0390625f;  // 1/(256*0.1), exact
constexpr float THR = 0.2f;
constexpr int CAP = 65536;   // candidate capacity (expected ~0 for this data)

typedef __attribute__((ext_vector_type(8))) short short8;
typedef __attribute__((ext_vector_type(4))) float f32x4;

__device__ __forceinline__ void atomicMaxPosF(float* addr, float v) {
  // valid for non-negative floats: uint bit order == float order
  atomicMax(reinterpret_cast<unsigned int*>(addr), __float_as_uint(v));
}

__device__ __forceinline__ bool valid80(int idx) {
  const int i = idx / 80;
  const int j = idx - i * 80;
  return (i >= 2) & (i < 78) & (j >= 2) & (j < 78);
}

// round-to-nearest-even fp32 -> bf16 bits
__device__ __forceinline__ unsigned short f2bf(float v) {
  unsigned u = __float_as_uint(v);
  return (unsigned short)((u + 0x7fffu + ((u >> 16) & 1u)) >> 16);
}

// The ONE conf expression. Computed exactly once per candidate (k_final1);
// k_final2 reuses the stored value -> == tests bitwise-consistent.
__device__ __forceinline__ float conf1(float s, float rs, float cs) {
  return expf(2.f * s) / (rs * cs);
}

typedef const __attribute__((address_space(1))) unsigned int guint;
typedef __attribute__((address_space(3))) unsigned int suint;
__device__ __forceinline__ void gload16(const void* g, void* l) {
  __builtin_amdgcn_global_load_lds((guint*)g, (suint*)l, 16, 0, 0);
}

// --- P-layout (R3/R4-verified: 0 bank conflicts) ----------------------------
// X' = [kstep 0..7][row 0..6399][granule g' 0..3][8 bf16]  (row block = 64 B)
// slot g' of row r holds k-granule g' ^ ((r>>1)&3).

// merged split: blocks [0,800) do x0 -> XA, [800,1600) do x1 -> XB,
// block 1600 zeroes the stats arrays (replaces the hipMemsetAsync node).
__global__ __launch_bounds__(256)
void k_split2(const float* __restrict__ X0, const float* __restrict__ X1,
              unsigned short* __restrict__ XA, unsigned short* __restrict__ XB,
              float* __restrict__ stats /* 4*Ldim floats + 4 uints */) {
  const int half = Ldim * 32 / 256;  // 800 blocks per input
  if (blockIdx.x == 2 * half) {
    for (int i = threadIdx.x; i < 4 * Ldim + 4; i += 256) stats[i] = 0.f;
    return;
  }
  const bool second = blockIdx.x >= half;
  const float* X = second ? X1 : X0;
  unsigned short* Xh = second ? XB : XA;
  const int g = (blockIdx.x - (second ? half : 0)) * 256 + threadIdx.x;
  const int r = g >> 5;
  const int gt = g & 31;
  const float* src = X + ((size_t)r << 8) + (gt << 3);
  const float4 a = *reinterpret_cast<const float4*>(src);
  const float4 b = *reinterpret_cast<const float4*>(src + 4);
  short8 hv;
  hv[0] = (short)f2bf(a.x); hv[1] = (short)f2bf(a.y);
  hv[2] = (short)f2bf(a.z); hv[3] = (short)f2bf(a.w);
  hv[4] = (short)f2bf(b.x); hv[5] = (short)f2bf(b.y);
  hv[6] = (short)f2bf(b.z); hv[7] = (short)f2bf(b.w);
  const int gp = (gt & 3) ^ ((r >> 1) & 3);
  const size_t dst = ((size_t)((gt >> 2) * Ldim + r) * 4 + gp) << 3;
  *reinterpret_cast<short8*>(Xh + dst) = hv;
}

// --- THE single GEMM pass, full-K-in-LDS structure.
// K=256 -> whole A-tile (64 KB) + whole B-tile (64 KB) fit in 128 KB LDS.
// Only TWO barriers per block (vs 16 in the 2-phase k-loop): batch-1 staging
// (A all + B ks0..1) -> barrier -> compute ks0..1 overlapping batch-2 staging
// (B ks2..7) + the output-tile zero-stores -> barrier -> compute ks2..7.
// Then stats epilogue + lower-bound candidate precheck:
//   s > 0.5*(ln(0.18) + ln(Rlow) + ln(Clow))  i.e. e^{2s} > 0.18*Rlow*Clow.
// Over-inclusive for conf>0.2 since Rlow<=Rsum, Clow<=Csum, 0.18<0.2 (11%
// slack >> fp rounding). A row/col whose true max is not a candidate has all
// conf < 0.2 there -> its RM/CM value is irrelevant.
__global__ __launch_bounds__(256)
void k_gemm_all(const unsigned short* __restrict__ A, const unsigned short* __restrict__ B,
                float* __restrict__ Rsum, float* __restrict__ Csum,
                unsigned int* __restrict__ cnt, unsigned int* __restrict__ cidx,
                float* __restrict__ csim, float* __restrict__ out) {
  __shared__ unsigned short sA[8][4096], sB[8][4096];  // 128 KB total
  const int tid = threadIdx.x;
  const int lane = tid & 63, wave = tid >> 6;
  const int wr = wave >> 1, wc = wave & 1;
  const int ll = lane & 15, lg = lane >> 4;
  const int arow = lane >> 2;       // staging: row within 16-row chunk
  const int gsel = (lane & 3) * 8;  // staging: granule (ushort offset)
  const int bx = blockIdx.x % (Sdim / 128);
  const int by = blockIdx.x / (Sdim / 128);
  const int m0 = by * 128, n0 = bx * 128;

  // one 16-row-chunk staging op (wave-uniform LDS base, per-lane global src)
  auto stA = [&](int ks, int p) {
    const int ch = wave * 2 + p;
    const size_t src = (size_t)ks * (Ldim * 32) + (size_t)(m0 + ch * 16 + arow) * 32 + gsel;
    gload16(A + src, &sA[ks][ch * 512]);
  };
  auto stB = [&](int ks, int p) {
    const int ch = wave * 2 + p;
    const size_t src = (size_t)ks * (Ldim * 32) + (size_t)(n0 + ch * 16 + arow) * 32 + gsel;
    gload16(B + src, &sB[ks][ch * 512]);
  };

  // batch 1: all of A, B k-segments 0..1
#pragma unroll
  for (int ks = 0; ks < 8; ++ks) { stA(ks, 0); stA(ks, 1); }
#pragma unroll
  for (int ks = 0; ks < 2; ++ks) { stB(ks, 0); stB(ks, 1); }
  __syncthreads();  // drain batch 1

  // batch 2: B k-segments 2..7 (drains at the SECOND barrier, hidden
  // under ks0..1 compute) + this block's output-tile zero-stores.
#pragma unroll
  for (int ks = 2; ks < 8; ++ks) { stB(ks, 0); stB(ks, 1); }
  {
    const float4 z = make_float4(0.f, 0.f, 0.f, 0.f);
#pragma unroll
    for (int i = 0; i < 16; ++i) {
      const int e = i * 256 + tid;   // 0..4095 float4 slots (32 per row)
      const int row = e >> 5;
      const int c4 = e & 31;
      *reinterpret_cast<float4*>(&out[(size_t)(m0 + row) * Sdim + n0 + c4 * 4]) = z;
    }
  }

  f32x4 acc[4][4];
#pragma unroll
  for (int mi = 0; mi < 4; ++mi)
#pragma unroll
    for (int ni = 0; ni < 4; ++ni) acc[mi][ni] = (f32x4){0.f, 0.f, 0.f, 0.f};

  auto rd = [&](const unsigned short (*S)[4096], int ks, int row) -> short8 {
    const int gp = lg ^ ((row >> 1) & 3);  // inverse granule swizzle
    return *reinterpret_cast<const short8*>(&S[ks][(row * 4 + gp) * 8]);
  };
  auto compute_ks = [&](int ks) {
    short8 af[4], bfv[4];
#pragma unroll
    for (int mi = 0; mi < 4; ++mi) af[mi] = rd(sA, ks, wr * 64 + mi * 16 + ll);
#pragma unroll
    for (int ni = 0; ni < 4; ++ni) bfv[ni] = rd(sB, ks, wc * 64 + ni * 16 + ll);
#pragma unroll
    for (int mi = 0; mi < 4; ++mi)
#pragma unroll
      for (int ni = 0; ni < 4; ++ni)
        acc[mi][ni] = __builtin_amdgcn_mfma_f32_16x16x32_bf16(af[mi], bfv[ni], acc[mi][ni], 0, 0, 0);
  };

  compute_ks(0);
  compute_ks(1);
  __syncthreads();  // drain batch 2 (B ks2..7) + zero-stores
#pragma unroll
  for (int ks = 2; ks < 8; ++ks) compute_ks(ks);

#pragma unroll
  for (int mi = 0; mi < 4; ++mi)
#pragma unroll
    for (int ni = 0; ni < 4; ++ni) acc[mi][ni] *= INV_CT;

  // C/D layout: col = lane&15, row = (lane>>4)*4 + reg  [m89/m91]
  // loop1: exp sums -> atomics; keep per-(mi,r) row sums and per-col sums.
  float re[16];
  float colp[4] = {0.f, 0.f, 0.f, 0.f};
#pragma unroll
  for (int mi = 0; mi < 4; ++mi)
#pragma unroll
    for (int r = 0; r < 4; ++r) {
      float s = 0.f;
#pragma unroll
      for (int ni = 0; ni < 4; ++ni) {
        const float e = expf(acc[mi][ni][r]);
        s += e;
        colp[ni] += e;
      }
      s += __shfl_xor(s, 1);
      s += __shfl_xor(s, 2);
      s += __shfl_xor(s, 4);
      s += __shfl_xor(s, 8);
      re[mi * 4 + r] = s;  // row sum over this wave's 64 cols (all 16 lanes)
      if (ll == 0)
        atomicAdd(&Rsum[m0 + wr * 64 + mi * 16 + lg * 4 + r], s);
    }
  float clw[4];
#pragma unroll
  for (int ni = 0; ni < 4; ++ni) {
    float c = colp[ni];
    c += __shfl_xor(c, 16);
    c += __shfl_xor(c, 32);
    clw[ni] = c;  // col sum over this wave's 64 rows (col = ni*16 + ll)
    if (lane < 16) atomicAdd(&Csum[n0 + wc * 64 + ni * 16 + lane], c);
  }

  // loop2: log-domain precheck, emit candidates (rare).
  constexpr float L018 = -1.7147984f;  // ln(0.18)
  float lc[4];
#pragma unroll
  for (int ni = 0; ni < 4; ++ni) lc[ni] = 0.5f * logf(clw[ni]);
#pragma unroll
  for (int mi = 0; mi < 4; ++mi)
#pragma unroll
    for (int r = 0; r < 4; ++r) {
      const float tr = 0.5f * (L018 + logf(re[mi * 4 + r]));
#pragma unroll
      for (int ni = 0; ni < 4; ++ni) {
        if (acc[mi][ni][r] > tr + lc[ni]) {
          const int row = m0 + wr * 64 + mi * 16 + lg * 4 + r;
          const int col = n0 + wc * 64 + ni * 16 + ll;
          const unsigned t = atomicAdd(cnt, 1u);
          if (t < CAP) {
            cidx[t] = (unsigned)row * Sdim + col;
            csim[t] = acc[mi][ni][r];
          }
        }
      }
    }
}

// --- k_final1: exact conf for each candidate (stored), RM/CM atomicMax.
__global__ __launch_bounds__(256)
void k_final1(const unsigned int* __restrict__ cnt, const unsigned int* __restrict__ cidx,
              const float* __restrict__ csim, const float* __restrict__ Rsum,
              const float* __restrict__ Csum, float* __restrict__ RM,
              float* __restrict__ CM, float* __restrict__ cconf) {
  const int n = (int)min(*cnt, (unsigned)CAP);
  for (int i = blockIdx.x * 256 + threadIdx.x; i < n; i += gridDim.x * 256) {
    const unsigned idx = cidx[i];
    const int l = idx / Sdim;
    const int s = idx - l * Sdim;
    const float c = conf1(csim[i], Rsum[l], Csum[s]);
    cconf[i] = c;
    atomicMaxPosF(&RM[l], c);
    atomicMaxPosF(&CM[s], c);
  }
}

// --- k_final2: final mask over candidates; scatter into zeroed output.
__global__ __launch_bounds__(256)
void k_final2(const unsigned int* __restrict__ cnt, const unsigned int* __restrict__ cidx,
              const float* __restrict__ cconf, const float* __restrict__ RM,
              const float* __restrict__ CM, float* __restrict__ out) {
  const int n = (int)min(*cnt, (unsigned)CAP);
  for (int i = blockIdx.x * 256 + threadIdx.x; i < n; i += gridDim.x * 256) {
    const unsigned idx = cidx[i];
    const int l = idx / Sdim;
    const int s = idx - l * Sdim;
    const float c = cconf[i];
    if (c > THR && valid80(l) && valid80(s) && c == RM[l] && c == CM[s])
      out[idx] = c;
  }
}

}  // namespace

extern "C" void kernel_launch(void* const* d_in, const int* in_sizes, int n_in,
                              void* d_out, int out_size, void* d_ws, size_t ws_size,
                              hipStream_t stream) {
  (void)in_sizes; (void)n_in; (void)out_size; (void)ws_size;
  const float* x0 = reinterpret_cast<const float*>(d_in[0]);
  const float* x1 = reinterpret_cast<const float*>(d_in[1]);
  float* out = reinterpret_cast<float*>(d_out);

  // ws layout: [Rsum 6400][Csum 6400][RM 6400][CM 6400][cnt 4]
  //            [cidx CAP][csim CAP][cconf CAP][XA][XB]
  float* Rsum = reinterpret_cast<float*>(d_ws);
  float* Csum = Rsum + Ldim;
  float* RM = Csum + Sdim;
  float* CM = RM + Ldim;
  unsigned int* cnt = reinterpret_cast<unsigned int*>(CM + Sdim);
  unsigned int* cidx = cnt + 4;
  float* csim = reinterpret_cast<float*>(cidx + CAP);
  float* cconf = csim + CAP;
  unsigned short* XA = reinterpret_cast<unsigned short*>(cconf + CAP);
  const size_t PSZ = (size_t)8 * Ldim * 32;  // ushorts per pre-split buffer
  unsigned short* XB = XA + PSZ;

  // stats zeroing is folded into k_split2's extra block (stats = Rsum..cnt)
  k_split2<<<2 * (Ldim * 32 / 256) + 1, 256, 0, stream>>>(x0, x1, XA, XB, Rsum);
  k_gemm_all<<<(Ldim / 128) * (Sdim / 128), 256, 0, stream>>>(
      XA, XB, Rsum, Csum, cnt, cidx, csim, out);
  k_final1<<<32, 256, 0, stream>>>(cnt, cidx, csim, Rsum, Csum, RM, CM, cconf);
  k_final2<<<32, 256, 0, stream>>>(cnt, cidx, cconf, RM, CM, out);
}

// Round 10
// 251.007 us; speedup vs baseline: 1.1514x; 1.1514x over previous
//
#include <hip/hip_runtime.h>

namespace {

constexpr int Ldim = 6400;   // rows (h0*w0)
constexpr int Sdim = 6400;   // cols (h1*w1)
constexpr float INV_CT = 0.0390625f;  // 1/(256*0.1), exact
constexpr float THR = 0.2f;
constexpr int CAP = 65536;   // candidate capacity (expected ~0 for this data)

typedef __attribute__((ext_vector_type(8))) short short8;
typedef __attribute__((ext_vector_type(4))) float f32x4;

__device__ __forceinline__ void atomicMaxPosF(float* addr, float v) {
  // valid for non-negative floats: uint bit order == float order
  atomicMax(reinterpret_cast<unsigned int*>(addr), __float_as_uint(v));
}

__device__ __forceinline__ bool valid80(int idx) {
  const int i = idx / 80;
  const int j = idx - i * 80;
  return (i >= 2) & (i < 78) & (j >= 2) & (j < 78);
}

// round-to-nearest-even fp32 -> bf16 bits
__device__ __forceinline__ unsigned short f2bf(float v) {
  unsigned u = __float_as_uint(v);
  return (unsigned short)((u + 0x7fffu + ((u >> 16) & 1u)) >> 16);
}

// The ONE conf expression. Computed exactly once per candidate (k_final1);
// k_final2 reuses the stored value -> == tests bitwise-consistent.
__device__ __forceinline__ float conf1(float s, float rs, float cs) {
  return expf(2.f * s) / (rs * cs);
}

typedef const __attribute__((address_space(1))) unsigned int guint;
typedef __attribute__((address_space(3))) unsigned int suint;
__device__ __forceinline__ void gload16(const void* g, void* l) {
  __builtin_amdgcn_global_load_lds((guint*)g, (suint*)l, 16, 0, 0);
}

// --- P-layout (R3/R4-verified: 0 bank conflicts) ----------------------------
// X' = [kstep 0..7][row 0..6399][granule g' 0..3][8 bf16]  (row block = 64 B)
// slot g' of row r holds k-granule g' ^ ((r>>1)&3).

// merged split: blocks [0,800) do x0 -> XA, [800,1600) do x1 -> XB,
// block 1600 zeroes the stats arrays (replaces the hipMemsetAsync node).
__global__ __launch_bounds__(256)
void k_split2(const float* __restrict__ X0, const float* __restrict__ X1,
              unsigned short* __restrict__ XA, unsigned short* __restrict__ XB,
              float* __restrict__ stats /* 4*Ldim floats + 4 uints */) {
  const int half = Ldim * 32 / 256;  // 800 blocks per input
  if (blockIdx.x == 2 * half) {
    for (int i = threadIdx.x; i < 4 * Ldim + 4; i += 256) stats[i] = 0.f;
    return;
  }
  const bool second = blockIdx.x >= half;
  const float* X = second ? X1 : X0;
  unsigned short* Xh = second ? XB : XA;
  const int g = (blockIdx.x - (second ? half : 0)) * 256 + threadIdx.x;
  const int r = g >> 5;
  const int gt = g & 31;
  const float* src = X + ((size_t)r << 8) + (gt << 3);
  const float4 a = *reinterpret_cast<const float4*>(src);
  const float4 b = *reinterpret_cast<const float4*>(src + 4);
  short8 hv;
  hv[0] = (short)f2bf(a.x); hv[1] = (short)f2bf(a.y);
  hv[2] = (short)f2bf(a.z); hv[3] = (short)f2bf(a.w);
  hv[4] = (short)f2bf(b.x); hv[5] = (short)f2bf(b.y);
  hv[6] = (short)f2bf(b.z); hv[7] = (short)f2bf(b.w);
  const int gp = (gt & 3) ^ ((r >> 1) & 3);
  const size_t dst = ((size_t)((gt >> 2) * Ldim + r) * 4 + gp) << 3;
  *reinterpret_cast<short8*>(Xh + dst) = hv;
}

// --- THE single GEMM pass (R7 structure: 128x128, BK=32, 4 waves, 32 KB
// double-buffered LDS, 2-phase stage-before-compute).  Changes vs R7:
//  * output-tile zero-stores interleaved into the k-loop (2 float4/thread/
//    k-step): store-acks drain concurrently with the prefetch-load latency
//    the barrier already waits on -> ~free (vs +26us as an entry burst).
//  * __expf/__logf in the stats epilogue (2^-21 rel err vs 4-orders slack).
//  * bijective XCD swizzle (m204; nwg=2500, r=4) for A-panel L2 locality.
// Candidate precheck (tile-local lower bounds, provably over-inclusive):
//   s > 0.5*(ln(0.18) + ln(Rlow) + ln(Clow))  i.e. e^{2s} > 0.18*Rlow*Clow.
__global__ __launch_bounds__(256)
void k_gemm_all(const unsigned short* __restrict__ A, const unsigned short* __restrict__ B,
                float* __restrict__ Rsum, float* __restrict__ Csum,
                unsigned int* __restrict__ cnt, unsigned int* __restrict__ cidx,
                float* __restrict__ csim, float* __restrict__ out) {
  __shared__ unsigned short sA[2][4096], sB[2][4096];
  const int tid = threadIdx.x;
  const int lane = tid & 63, wave = tid >> 6;
  const int wr = wave >> 1, wc = wave & 1;
  const int ll = lane & 15, lg = lane >> 4;
  const int arow = lane >> 2;       // staging: row within 16-row chunk
  const int gsel = (lane & 3) * 8;  // staging: granule (ushort offset)

  // bijective XCD swizzle (m204): 8 XCDs, nwg = 2500 (q=312, r=4)
  const int nwg = (Ldim / 128) * (Sdim / 128);
  const int q = nwg >> 3, rr = nwg & 7;
  const int xcd = blockIdx.x & 7, bidx = blockIdx.x >> 3;
  const int wgid = (xcd < rr ? xcd * (q + 1) : rr * (q + 1) + (xcd - rr) * q) + bidx;
  const int bx = wgid % (Sdim / 128);
  const int by = wgid / (Sdim / 128);
  const int m0 = by * 128, n0 = bx * 128;

  f32x4 acc[4][4];
#pragma unroll
  for (int mi = 0; mi < 4; ++mi)
#pragma unroll
    for (int ni = 0; ni < 4; ++ni) acc[mi][ni] = (f32x4){0.f, 0.f, 0.f, 0.f};

  auto stage = [&](int slot, int ks) {
    const size_t kb = (size_t)ks * (Ldim * 32);
#pragma unroll
    for (int p = 0; p < 2; ++p) {
      const int ch = wave * 2 + p;
      const size_t asrc = kb + (size_t)(m0 + ch * 16 + arow) * 32 + gsel;
      const size_t bsrc = kb + (size_t)(n0 + ch * 16 + arow) * 32 + gsel;
      gload16(A + asrc, &sA[slot][ch * 512]);
      gload16(B + bsrc, &sB[slot][ch * 512]);
    }
  };

  stage(0, 0);
  __syncthreads();  // compiler drains vmcnt before s_barrier

  for (int ks = 0; ks < 8; ++ks) {
    const int cur = ks & 1;
    if (ks < 7) stage(cur ^ 1, ks + 1);  // prefetch overlaps this tile's MFMA

    // two zero-store float4s of this block's out tile per k-step (16 total);
    // their write-acks drain under the same barrier wait as the prefetch.
    {
      const float4 z = make_float4(0.f, 0.f, 0.f, 0.f);
#pragma unroll
      for (int p = 0; p < 2; ++p) {
        const int e = (ks * 2 + p) * 256 + tid;  // 0..4095 float4 slots
        const int row = e >> 5;
        const int c4 = e & 31;
        *reinterpret_cast<float4*>(&out[(size_t)(m0 + row) * Sdim + n0 + c4 * 4]) = z;
      }
    }

    auto rd = [&](unsigned short* S, int row) -> short8 {
      const int gp = lg ^ ((row >> 1) & 3);  // inverse granule swizzle
      return *reinterpret_cast<const short8*>(&S[(row * 4 + gp) * 8]);
    };
    short8 af[4], bfv[4];
#pragma unroll
    for (int mi = 0; mi < 4; ++mi) af[mi] = rd(sA[cur], wr * 64 + mi * 16 + ll);
#pragma unroll
    for (int ni = 0; ni < 4; ++ni) bfv[ni] = rd(sB[cur], wc * 64 + ni * 16 + ll);
#pragma unroll
    for (int mi = 0; mi < 4; ++mi)
#pragma unroll
      for (int ni = 0; ni < 4; ++ni)
        acc[mi][ni] = __builtin_amdgcn_mfma_f32_16x16x32_bf16(af[mi], bfv[ni], acc[mi][ni], 0, 0, 0);

    __syncthreads();  // drains prefetch + zero-stores + lgkm before swap
  }

#pragma unroll
  for (int mi = 0; mi < 4; ++mi)
#pragma unroll
    for (int ni = 0; ni < 4; ++ni) acc[mi][ni] *= INV_CT;

  // C/D layout: col = lane&15, row = (lane>>4)*4 + reg  [m89/m91]
  // loop1: exp sums -> atomics; keep per-(mi,r) row sums and per-col sums.
  float re[16];
  float colp[4] = {0.f, 0.f, 0.f, 0.f};
#pragma unroll
  for (int mi = 0; mi < 4; ++mi)
#pragma unroll
    for (int r = 0; r < 4; ++r) {
      float s = 0.f;
#pragma unroll
      for (int ni = 0; ni < 4; ++ni) {
        const float e = __expf(acc[mi][ni][r]);
        s += e;
        colp[ni] += e;
      }
      s += __shfl_xor(s, 1);
      s += __shfl_xor(s, 2);
      s += __shfl_xor(s, 4);
      s += __shfl_xor(s, 8);
      re[mi * 4 + r] = s;  // row sum over this wave's 64 cols (all 16 lanes)
      if (ll == 0)
        atomicAdd(&Rsum[m0 + wr * 64 + mi * 16 + lg * 4 + r], s);
    }
  float clw[4];
#pragma unroll
  for (int ni = 0; ni < 4; ++ni) {
    float c = colp[ni];
    c += __shfl_xor(c, 16);
    c += __shfl_xor(c, 32);
    clw[ni] = c;  // col sum over this wave's 64 rows (col = ni*16 + ll)
    if (lane < 16) atomicAdd(&Csum[n0 + wc * 64 + ni * 16 + lane], c);
  }

  // loop2: log-domain precheck, emit candidates (rare).
  constexpr float L018 = -1.7147984f;  // ln(0.18)
  float lc[4];
#pragma unroll
  for (int ni = 0; ni < 4; ++ni) lc[ni] = 0.5f * __logf(clw[ni]);
#pragma unroll
  for (int mi = 0; mi < 4; ++mi)
#pragma unroll
    for (int r = 0; r < 4; ++r) {
      const float tr = 0.5f * (L018 + __logf(re[mi * 4 + r]));
#pragma unroll
      for (int ni = 0; ni < 4; ++ni) {
        if (acc[mi][ni][r] > tr + lc[ni]) {
          const int row = m0 + wr * 64 + mi * 16 + lg * 4 + r;
          const int col = n0 + wc * 64 + ni * 16 + ll;
          const unsigned t = atomicAdd(cnt, 1u);
          if (t < CAP) {
            cidx[t] = (unsigned)row * Sdim + col;
            csim[t] = acc[mi][ni][r];
          }
        }
      }
    }
}

// --- k_final1: exact conf for each candidate (stored), RM/CM atomicMax.
__global__ __launch_bounds__(256)
void k_final1(const unsigned int* __restrict__ cnt, const unsigned int* __restrict__ cidx,
              const float* __restrict__ csim, const float* __restrict__ Rsum,
              const float* __restrict__ Csum, float* __restrict__ RM,
              float* __restrict__ CM, float* __restrict__ cconf) {
  const int n = (int)min(*cnt, (unsigned)CAP);
  for (int i = blockIdx.x * 256 + threadIdx.x; i < n; i += gridDim.x * 256) {
    const unsigned idx = cidx[i];
    const int l = idx / Sdim;
    const int s = idx - l * Sdim;
    const float c = conf1(csim[i], Rsum[l], Csum[s]);
    cconf[i] = c;
    atomicMaxPosF(&RM[l], c);
    atomicMaxPosF(&CM[s], c);
  }
}

// --- k_final2: final mask over candidates; scatter into zeroed output.
__global__ __launch_bounds__(256)
void k_final2(const unsigned int* __restrict__ cnt, const unsigned int* __restrict__ cidx,
              const float* __restrict__ cconf, const float* __restrict__ RM,
              const float* __restrict__ CM, float* __restrict__ out) {
  const int n = (int)min(*cnt, (unsigned)CAP);
  for (int i = blockIdx.x * 256 + threadIdx.x; i < n; i += gridDim.x * 256) {
    const unsigned idx = cidx[i];
    const int l = idx / Sdim;
    const int s = idx - l * Sdim;
    const float c = cconf[i];
    if (c > THR && valid80(l) && valid80(s) && c == RM[l] && c == CM[s])
      out[idx] = c;
  }
}

}  // namespace

extern "C" void kernel_launch(void* const* d_in, const int* in_sizes, int n_in,
                              void* d_out, int out_size, void* d_ws, size_t ws_size,
                              hipStream_t stream) {
  (void)in_sizes; (void)n_in; (void)out_size; (void)ws_size;
  const float* x0 = reinterpret_cast<const float*>(d_in[0]);
  const float* x1 = reinterpret_cast<const float*>(d_in[1]);
  float* out = reinterpret_cast<float*>(d_out);

  // ws layout: [Rsum 6400][Csum 6400][RM 6400][CM 6400][cnt 4]
  //            [cidx CAP][csim CAP][cconf CAP][XA][XB]
  float* Rsum = reinterpret_cast<float*>(d_ws);
  float* Csum = Rsum + Ldim;
  float* RM = Csum + Sdim;
  float* CM = RM + Ldim;
  unsigned int* cnt = reinterpret_cast<unsigned int*>(CM + Sdim);
  unsigned int* cidx = cnt + 4;
  float* csim = reinterpret_cast<float*>(cidx + CAP);
  float* cconf = csim + CAP;
  unsigned short* XA = reinterpret_cast<unsigned short*>(cconf + CAP);
  const size_t PSZ = (size_t)8 * Ldim * 32;  // ushorts per pre-split buffer
  unsigned short* XB = XA + PSZ;

  // stats zeroing is folded into k_split2's extra block (stats = Rsum..cnt)
  k_split2<<<2 * (Ldim * 32 / 256) + 1, 256, 0, stream>>>(x0, x1, XA, XB, Rsum);
  k_gemm_all<<<(Ldim / 128) * (Sdim / 128), 256, 0, stream>>>(
      XA, XB, Rsum, Csum, cnt, cidx, csim, out);
  k_final1<<<32, 256, 0, stream>>>(cnt, cidx, csim, Rsum, Csum, RM, CM, cconf);
  k_final2<<<32, 256, 0, stream>>>(cnt, cidx, cconf, RM, CM, out);
}

// Round 11
// 242.167 us; speedup vs baseline: 1.1934x; 1.0365x over previous
//
#include <hip/hip_runtime.h>

namespace {

constexpr int Ldim = 6400;   // rows (h0*w0)
constexpr int Sdim = 6400;   // cols (h1*w1)
constexpr float INV_CT = 0.0390625f;  // 1/(256*0.1), exact
constexpr float THR = 0.2f;
constexpr int CAP = 65536;   // candidate capacity (expected ~0 for this data)

typedef __attribute__((ext_vector_type(8))) short short8;
typedef __attribute__((ext_vector_type(4))) float f32x4;

__device__ __forceinline__ void atomicMaxPosF(float* addr, float v) {
  // valid for non-negative floats: uint bit order == float order
  atomicMax(reinterpret_cast<unsigned int*>(addr), __float_as_uint(v));
}

__device__ __forceinline__ bool valid80(int idx) {
  const int i = idx / 80;
  const int j = idx - i * 80;
  return (i >= 2) & (i < 78) & (j >= 2) & (j < 78);
}

// round-to-nearest-even fp32 -> bf16 bits
__device__ __forceinline__ unsigned short f2bf(float v) {
  unsigned u = __float_as_uint(v);
  return (unsigned short)((u + 0x7fffu + ((u >> 16) & 1u)) >> 16);
}

// The ONE conf expression. Computed exactly once per candidate (k_final1);
// k_final2 reuses the stored value -> == tests bitwise-consistent.
__device__ __forceinline__ float conf1(float s, float rs, float cs) {
  return expf(2.f * s) / (rs * cs);
}

typedef const __attribute__((address_space(1))) unsigned int guint;
typedef __attribute__((address_space(3))) unsigned int suint;
__device__ __forceinline__ void gload16(const void* g, void* l) {
  __builtin_amdgcn_global_load_lds((guint*)g, (suint*)l, 16, 0, 0);
}

// --- P-layout (R3/R4-verified: 0 bank conflicts) ----------------------------
// X' = [kstep 0..7][row 0..6399][granule g' 0..3][8 bf16]  (row block = 64 B)
// slot g' of row r holds k-granule g' ^ ((r>>1)&3).

// merged split: blocks [0,800) do x0 -> XA, [800,1600) do x1 -> XB,
// block 1600 zeroes the stats arrays (replaces the hipMemsetAsync node).
__global__ __launch_bounds__(256)
void k_split2(const float* __restrict__ X0, const float* __restrict__ X1,
              unsigned short* __restrict__ XA, unsigned short* __restrict__ XB,
              float* __restrict__ stats /* 4*Ldim floats + 4 uints */) {
  const int half = Ldim * 32 / 256;  // 800 blocks per input
  if (blockIdx.x == 2 * half) {
    for (int i = threadIdx.x; i < 4 * Ldim + 4; i += 256) stats[i] = 0.f;
    return;
  }
  const bool second = blockIdx.x >= half;
  const float* X = second ? X1 : X0;
  unsigned short* Xh = second ? XB : XA;
  const int g = (blockIdx.x - (second ? half : 0)) * 256 + threadIdx.x;
  const int r = g >> 5;
  const int gt = g & 31;
  const float* src = X + ((size_t)r << 8) + (gt << 3);
  const float4 a = *reinterpret_cast<const float4*>(src);
  const float4 b = *reinterpret_cast<const float4*>(src + 4);
  short8 hv;
  hv[0] = (short)f2bf(a.x); hv[1] = (short)f2bf(a.y);
  hv[2] = (short)f2bf(a.z); hv[3] = (short)f2bf(a.w);
  hv[4] = (short)f2bf(b.x); hv[5] = (short)f2bf(b.y);
  hv[6] = (short)f2bf(b.z); hv[7] = (short)f2bf(b.w);
  const int gp = (gt & 3) ^ ((r >> 1) & 3);
  const size_t dst = ((size_t)((gt >> 2) * Ldim + r) * 4 + gp) << 3;
  *reinterpret_cast<short8*>(Xh + dst) = hv;
}

// --- THE single GEMM pass (128x128, BK=32, 4 waves, 32 KB dbuf LDS).
// T4 counted-vmcnt schedule (m218 mechanism): per k-step
//   stage(next)+2 zero-stores -> s_waitcnt vmcnt(6) [retire PREV stage only,
//   this step's 6 ops stay in flight] -> s_barrier [publish cur] ->
//   ds_read+MFMA -> s_barrier [reads done before next overwrites cur].
// No vmcnt(0) drains anywhere in the loop; zero-stores retire lazily.
// No XCD swizzle (R10 measured: FETCH 46->67 MB, dur up -> reverted).
// Candidate precheck (tile-local lower bounds, provably over-inclusive):
//   s > 0.5*(ln(0.18) + ln(Rlow) + ln(Clow))  i.e. e^{2s} > 0.18*Rlow*Clow.
__global__ __launch_bounds__(256)
void k_gemm_all(const unsigned short* __restrict__ A, const unsigned short* __restrict__ B,
                float* __restrict__ Rsum, float* __restrict__ Csum,
                unsigned int* __restrict__ cnt, unsigned int* __restrict__ cidx,
                float* __restrict__ csim, float* __restrict__ out) {
  __shared__ unsigned short sA[2][4096], sB[2][4096];
  const int tid = threadIdx.x;
  const int lane = tid & 63, wave = tid >> 6;
  const int wr = wave >> 1, wc = wave & 1;
  const int ll = lane & 15, lg = lane >> 4;
  const int arow = lane >> 2;       // staging: row within 16-row chunk
  const int gsel = (lane & 3) * 8;  // staging: granule (ushort offset)
  const int bx = blockIdx.x % (Sdim / 128);
  const int by = blockIdx.x / (Sdim / 128);
  const int m0 = by * 128, n0 = bx * 128;

  f32x4 acc[4][4];
#pragma unroll
  for (int mi = 0; mi < 4; ++mi)
#pragma unroll
    for (int ni = 0; ni < 4; ++ni) acc[mi][ni] = (f32x4){0.f, 0.f, 0.f, 0.f};

  auto stage = [&](int slot, int ks) {  // 4 vmem ops/thread
    const size_t kb = (size_t)ks * (Ldim * 32);
#pragma unroll
    for (int p = 0; p < 2; ++p) {
      const int ch = wave * 2 + p;
      const size_t asrc = kb + (size_t)(m0 + ch * 16 + arow) * 32 + gsel;
      const size_t bsrc = kb + (size_t)(n0 + ch * 16 + arow) * 32 + gsel;
      gload16(A + asrc, &sA[slot][ch * 512]);
      gload16(B + bsrc, &sB[slot][ch * 512]);
    }
  };

  stage(0, 0);  // 4 ops outstanding

  for (int ks = 0; ks < 8; ++ks) {
    const int cur = ks & 1;
    if (ks < 7) stage(cur ^ 1, ks + 1);  // 4 ops into the other slot

    // two zero-store float4s of this block's out tile per k-step (16 total);
    // they ride the vmem pipeline and retire under NEXT iter's counted wait.
    {
      const float4 z = make_float4(0.f, 0.f, 0.f, 0.f);
#pragma unroll
      for (int p = 0; p < 2; ++p) {
        const int e = (ks * 2 + p) * 256 + tid;  // 0..4095 float4 slots
        const int row = e >> 5;
        const int c4 = e & 31;
        *reinterpret_cast<float4*>(&out[(size_t)(m0 + row) * Sdim + n0 + c4 * 4]) = z;
      }
    }

    // retire everything older than this iter's issues -> prev stage landed.
    if (ks < 7) asm volatile("s_waitcnt vmcnt(6)" ::: "memory");
    else        asm volatile("s_waitcnt vmcnt(2)" ::: "memory");
    __builtin_amdgcn_sched_barrier(0);  // rule #18: pin code after the wait
    __builtin_amdgcn_s_barrier();       // publish slot cur across waves

    auto rd = [&](unsigned short* S, int row) -> short8 {
      const int gp = lg ^ ((row >> 1) & 3);  // inverse granule swizzle
      return *reinterpret_cast<const short8*>(&S[(row * 4 + gp) * 8]);
    };
    short8 af[4], bfv[4];
#pragma unroll
    for (int mi = 0; mi < 4; ++mi) af[mi] = rd(sA[cur], wr * 64 + mi * 16 + ll);
#pragma unroll
    for (int ni = 0; ni < 4; ++ni) bfv[ni] = rd(sB[cur], wc * 64 + ni * 16 + ll);
#pragma unroll
    for (int mi = 0; mi < 4; ++mi)
#pragma unroll
      for (int ni = 0; ni < 4; ++ni)
        acc[mi][ni] = __builtin_amdgcn_mfma_f32_16x16x32_bf16(af[mi], bfv[ni], acc[mi][ni], 0, 0, 0);

    // reads of cur complete (lgkmcnt before MFMA issue) -> safe for iter
    // ks+1 to overwrite cur after this barrier. NO vmcnt drain here.
    __builtin_amdgcn_s_barrier();
  }

#pragma unroll
  for (int mi = 0; mi < 4; ++mi)
#pragma unroll
    for (int ni = 0; ni < 4; ++ni) acc[mi][ni] *= INV_CT;

  // C/D layout: col = lane&15, row = (lane>>4)*4 + reg  [m89/m91]
  // loop1: exp sums -> atomics; keep per-(mi,r) row sums and per-col sums.
  float re[16];
  float colp[4] = {0.f, 0.f, 0.f, 0.f};
#pragma unroll
  for (int mi = 0; mi < 4; ++mi)
#pragma unroll
    for (int r = 0; r < 4; ++r) {
      float s = 0.f;
#pragma unroll
      for (int ni = 0; ni < 4; ++ni) {
        const float e = __expf(acc[mi][ni][r]);
        s += e;
        colp[ni] += e;
      }
      s += __shfl_xor(s, 1);
      s += __shfl_xor(s, 2);
      s += __shfl_xor(s, 4);
      s += __shfl_xor(s, 8);
      re[mi * 4 + r] = s;  // row sum over this wave's 64 cols (all 16 lanes)
      if (ll == 0)
        atomicAdd(&Rsum[m0 + wr * 64 + mi * 16 + lg * 4 + r], s);
    }
  float clw[4];
#pragma unroll
  for (int ni = 0; ni < 4; ++ni) {
    float c = colp[ni];
    c += __shfl_xor(c, 16);
    c += __shfl_xor(c, 32);
    clw[ni] = c;  // col sum over this wave's 64 rows (col = ni*16 + ll)
    if (lane < 16) atomicAdd(&Csum[n0 + wc * 64 + ni * 16 + lane], c);
  }

  // loop2: log-domain precheck, emit candidates (rare).
  constexpr float L018 = -1.7147984f;  // ln(0.18)
  float lc[4];
#pragma unroll
  for (int ni = 0; ni < 4; ++ni) lc[ni] = 0.5f * __logf(clw[ni]);
#pragma unroll
  for (int mi = 0; mi < 4; ++mi)
#pragma unroll
    for (int r = 0; r < 4; ++r) {
      const float tr = 0.5f * (L018 + __logf(re[mi * 4 + r]));
#pragma unroll
      for (int ni = 0; ni < 4; ++ni) {
        if (acc[mi][ni][r] > tr + lc[ni]) {
          const int row = m0 + wr * 64 + mi * 16 + lg * 4 + r;
          const int col = n0 + wc * 64 + ni * 16 + ll;
          const unsigned t = atomicAdd(cnt, 1u);
          if (t < CAP) {
            cidx[t] = (unsigned)row * Sdim + col;
            csim[t] = acc[mi][ni][r];
          }
        }
      }
    }
}

// --- k_final1: exact conf for each candidate (stored), RM/CM atomicMax.
__global__ __launch_bounds__(256)
void k_final1(const unsigned int* __restrict__ cnt, const unsigned int* __restrict__ cidx,
              const float* __restrict__ csim, const float* __restrict__ Rsum,
              const float* __restrict__ Csum, float* __restrict__ RM,
              float* __restrict__ CM, float* __restrict__ cconf) {
  const int n = (int)min(*cnt, (unsigned)CAP);
  for (int i = blockIdx.x * 256 + threadIdx.x; i < n; i += gridDim.x * 256) {
    const unsigned idx = cidx[i];
    const int l = idx / Sdim;
    const int s = idx - l * Sdim;
    const float c = conf1(csim[i], Rsum[l], Csum[s]);
    cconf[i] = c;
    atomicMaxPosF(&RM[l], c);
    atomicMaxPosF(&CM[s], c);
  }
}

// --- k_final2: final mask over candidates; scatter into zeroed output.
__global__ __launch_bounds__(256)
void k_final2(const unsigned int* __restrict__ cnt, const unsigned int* __restrict__ cidx,
              const float* __restrict__ cconf, const float* __restrict__ RM,
              const float* __restrict__ CM, float* __restrict__ out) {
  const int n = (int)min(*cnt, (unsigned)CAP);
  for (int i = blockIdx.x * 256 + threadIdx.x; i < n; i += gridDim.x * 256) {
    const unsigned idx = cidx[i];
    const int l = idx / Sdim;
    const int s = idx - l * Sdim;
    const float c = cconf[i];
    if (c > THR && valid80(l) && valid80(s) && c == RM[l] && c == CM[s])
      out[idx] = c;
  }
}

}  // namespace

extern "C" void kernel_launch(void* const* d_in, const int* in_sizes, int n_in,
                              void* d_out, int out_size, void* d_ws, size_t ws_size,
                              hipStream_t stream) {
  (void)in_sizes; (void)n_in; (void)out_size; (void)ws_size;
  const float* x0 = reinterpret_cast<const float*>(d_in[0]);
  const float* x1 = reinterpret_cast<const float*>(d_in[1]);
  float* out = reinterpret_cast<float*>(d_out);

  // ws layout: [Rsum 6400][Csum 6400][RM 6400][CM 6400][cnt 4]
  //            [cidx CAP][csim CAP][cconf CAP][XA][XB]
  float* Rsum = reinterpret_cast<float*>(d_ws);
  float* Csum = Rsum + Ldim;
  float* RM = Csum + Sdim;
  float* CM = RM + Ldim;
  unsigned int* cnt = reinterpret_cast<unsigned int*>(CM + Sdim);
  unsigned int* cidx = cnt + 4;
  float* csim = reinterpret_cast<float*>(cidx + CAP);
  float* cconf = csim + CAP;
  unsigned short* XA = reinterpret_cast<unsigned short*>(cconf + CAP);
  const size_t PSZ = (size_t)8 * Ldim * 32;  // ushorts per pre-split buffer
  unsigned short* XB = XA + PSZ;

  // stats zeroing is folded into k_split2's extra block (stats = Rsum..cnt)
  k_split2<<<2 * (Ldim * 32 / 256) + 1, 256, 0, stream>>>(x0, x1, XA, XB, Rsum);
  k_gemm_all<<<(Ldim / 128) * (Sdim / 128), 256, 0, stream>>>(
      XA, XB, Rsum, Csum, cnt, cidx, csim, out);
  k_final1<<<32, 256, 0, stream>>>(cnt, cidx, csim, Rsum, Csum, RM, CM, cconf);
  k_final2<<<32, 256, 0, stream>>>(cnt, cidx, cconf, RM, CM, out);
}